// Round 4
// baseline (641.113 us; speedup 1.0000x reference)
//
#include <hip/hip_runtime.h>
#include <cstddef>

#define NE 16384
#define NN 4096
#define BG 16
#define NT 16      // nodes per conv tile
#define ACH 8      // a-chunk size (4 chunks of 8 per block, 2 y-blocks -> 64)

__device__ __forceinline__ float lrelu(float v){ return v >= 0.f ? v : 0.01f*v; }
__device__ __forceinline__ float sigm(float v){ return 1.f/(1.f + expf(-v)); }

// ---------------- setup: W8T, h0, he, deg(dst), cnt(src) ----------------
__global__ __launch_bounds__(256) void setup_kernel(
    const float* __restrict__ x, const float* __restrict__ ea,
    const int* __restrict__ ei,
    const float* __restrict__ W0, const float* __restrict__ b0,
    const float* __restrict__ We1, const float* __restrict__ be1,
    const float* __restrict__ Wih, const float* __restrict__ Whh,
    float* __restrict__ W8T,
    float* __restrict__ h, float* __restrict__ he,
    int* __restrict__ deg, int* __restrict__ cnt)
{
    int t = blockIdx.x*256 + threadIdx.x;   // grid: 4096x256 = 1048576
    {   // he: [E,64]  lrelu(edge_attr @ We1 + be1)
        int e = t >> 6, f = t & 63;
        float v = be1[f];
        #pragma unroll
        for (int d = 0; d < 4; ++d) v += ea[e*4+d]*We1[d*64+f];
        he[t] = lrelu(v);
    }
    if (t < NN*64) {    // h0 = lrelu(x @ W0 + b0)
        int n = t >> 6, f = t & 63;
        float v = b0[f];
        #pragma unroll
        for (int d = 0; d < 3; ++d) v += x[n*3+d]*W0[d*64+f];
        h[t] = lrelu(v);
    }
    if (t < 32768) {    // W8T[k][g][8] = {Wih_r,Wih_z,Wih_n,Whh_r,Whh_z,Whh_n,0,0}
        int k = t >> 9, g = (t >> 3) & 63, j = t & 7;
        float v = 0.f;
        if (j < 3)      v = Wih[(j*64+g)*64 + k];
        else if (j < 6) v = Whh[((j-3)*64+g)*64 + k];
        W8T[t] = v;
    }
    if (t < NE) {
        atomicAdd(&deg[ei[NE + t]], 1);   // in-degree (dst) for mean aggr
        atomicAdd(&cnt[ei[t]], 1);        // out-degree (src) for edge sort
    }
}

// ---------------- exclusive scan of cnt[4096] -> offs[4097] (1 block) ----------------
__global__ __launch_bounds__(256) void scan_kernel(const int* __restrict__ cnt,
                                                   int* __restrict__ offs)
{
    __shared__ int ps[256];
    int t = threadIdx.x;
    int base = t*16;
    int loc[16];
    int s = 0;
    #pragma unroll
    for (int i = 0; i < 16; ++i) { loc[i] = s; s += cnt[base+i]; }
    ps[t] = s; __syncthreads();
    for (int off = 1; off < 256; off <<= 1) {
        int v = 0;
        if (t >= off) v = ps[t-off];
        __syncthreads();
        if (t >= off) ps[t] += v;
        __syncthreads();
    }
    int pre = (t == 0) ? 0 : ps[t-1];
    #pragma unroll
    for (int i = 0; i < 16; ++i) offs[base+i] = pre + loc[i];
    if (t == 255) offs[NN] = pre + s;
}

// ---------------- scatter: build src-sorted edge arrays ----------------
__global__ __launch_bounds__(256) void scatter_kernel(
    const int* __restrict__ ei, const int* __restrict__ offs,
    int* __restrict__ cnt,  // consumed as cursor via atomicSub
    int* __restrict__ srcs, int* __restrict__ dsts, int* __restrict__ perm)
{
    int e = blockIdx.x*256 + threadIdx.x;
    if (e >= NE) return;
    int s = ei[e], d = ei[NE + e];
    int old = atomicSub(&cnt[s], 1);
    int pos = offs[s] + old - 1;
    srcs[pos] = s; dsts[pos] = d; perm[pos] = e;
}

// ---------------- gather he rows into src-sorted order ----------------
__global__ __launch_bounds__(256) void reorder_kernel(
    const float* __restrict__ he, const int* __restrict__ perm,
    float* __restrict__ he_srt)
{
    int t = blockIdx.x*256 + threadIdx.x;   // 4096 x 256 = NE*64
    he_srt[t] = he[(size_t)perm[t>>6]*64 + (t & 63)];
}

// ---------------- inv_deg + per-graph node ranges ----------------
__global__ __launch_bounds__(256) void inv_range_kernel(
    const int* __restrict__ deg, const int* __restrict__ batch,
    float* __restrict__ inv_deg, int* __restrict__ gstart, int* __restrict__ gend)
{
    int n = blockIdx.x*256 + threadIdx.x;   // 16 blocks -> 4096
    if (n >= NN) return;
    inv_deg[n] = 1.f / fmaxf((float)deg[n], 1.f);
    int b  = batch[n];
    int bp = (n == 0)    ? -1 : batch[n-1];
    int bn = (n == NN-1) ? BG : batch[n+1];
    for (int g = bp+1; g <= b; ++g) gstart[g] = n;
    for (int g = b;   g <  bn; ++g) gend[g]   = n+1;
    if (n == 0)    for (int g = 0;   g < b;  ++g) gend[g]   = 0;
    if (n == NN-1) for (int g = b+1; g < BG; ++g) gstart[g] = NN;
}

// ---------------- fused conv: T-chunk in LDS + edge messages ----------------
// 512-thread blocks, grid (NN/NT, 2). Round-3 lesson: 1024-thr blocks at
// VGPR>=64 cap at 16 waves/CU (1 block) -> phases serialize. Two 512-thr
// blocks (44 KB LDS each) co-reside (16 waves/CU): block (x,0) and (x,1)
// land on the same CU, overlap T-GEMM (VALU) with edge phase (LDS/atomics),
// and share L1-hot h/he tiles. Per block: 32 a-values in 4 chunks of 8.
// Each y-half scatters to its own agg buffer.
__global__ __launch_bounds__(512) void conv_kernel(
    const float* __restrict__ h, const float* __restrict__ We2,
    const float* __restrict__ be2, const float* __restrict__ he_srt,
    const int* __restrict__ offs, const int* __restrict__ srcs,
    const int* __restrict__ dsts, float* __restrict__ agg)
{
    __shared__ float hsT[64][NT];        // 4 KB
    __shared__ float Tb [NT][64];        // 4 KB
    __shared__ float Tc [ACH][NT][64];   // 32 KB
    __shared__ float he_s[128][ACH];     // 4 KB   (total 44 KB -> 2 blocks/CU)
    int t  = threadIdx.x;
    int n0 = blockIdx.x * NT;
    int a0 = blockIdx.y * 32;
    float* aggp = agg + (size_t)blockIdx.y * NN * 64;

    #pragma unroll
    for (int r = 0; r < 2; ++r) {       // stage h tile transposed (1024 elems)
        int idx = t + r*512;
        int n = idx >> 6, i = idx & 63;
        hsT[i][n] = h[(size_t)(n0+n)*64 + i];
    }
    __syncthreads();
    if (blockIdx.y == 0) {   // Tb[n][f] = sum_i h[n,i] * be2[i*64+f]
        #pragma unroll
        for (int r = 0; r < 2; ++r) {
            int idx = t + r*512;
            int n = idx >> 6, f = idx & 63;
            float acc = 0.f;
            #pragma unroll 8
            for (int i = 0; i < 64; ++i) acc += hsT[i][n] * be2[i*64+f];
            Tb[n][f] = acc;
        }
    }

    int ebase = offs[n0];
    int ecnt  = offs[n0+NT] - ebase;
    int eend  = ebase + ecnt;
    int slot  = t >> 4;            // 0..31 edge slots
    int f4    = (t & 15) * 4;      // 4 output features per thread
    int nl0=-1, dt0=0, nl1=-1, dt1=0, nl2=-1, dt2=0, nl3=-1, dt3=0;
    {
        int e0 = ebase + slot;
        if (slot      < ecnt) { nl0 = srcs[e0]    - n0; dt0 = dsts[e0];    }
        if (slot + 32 < ecnt) { nl1 = srcs[e0+32] - n0; dt1 = dsts[e0+32]; }
        if (slot + 64 < ecnt) { nl2 = srcs[e0+64] - n0; dt2 = dsts[e0+64]; }
        if (slot + 96 < ecnt) { nl3 = srcs[e0+96] - n0; dt3 = dsts[e0+96]; }
    }
    float4 m0 = {0,0,0,0}, m1 = {0,0,0,0}, m2 = {0,0,0,0}, m3 = {0,0,0,0};

    int aT = t >> 6;               // 0..7   a' within chunk
    int nT = ((t >> 4) & 3) * 4;   // 4 n per thread
    int fT = (t & 15) * 4;         // 4 f per thread

    #pragma unroll
    for (int c = 0; c < 4; ++c) {
        int ac = a0 + c*ACH;
        // ---- compute T chunk into registers ----
        const float* Wp = We2 + (size_t)(ac + aT)*4096 + fT;
        float4 A0 = {0,0,0,0}, A1 = {0,0,0,0}, A2 = {0,0,0,0}, A3 = {0,0,0,0};
        #pragma unroll 8
        for (int i = 0; i < 64; ++i) {
            float4 w  = *(const float4*)(Wp + (size_t)i*64);
            float4 hv = *(const float4*)&hsT[i][nT];
            A0.x += hv.x*w.x; A0.y += hv.x*w.y; A0.z += hv.x*w.z; A0.w += hv.x*w.w;
            A1.x += hv.y*w.x; A1.y += hv.y*w.y; A1.z += hv.y*w.z; A1.w += hv.y*w.w;
            A2.x += hv.z*w.x; A2.y += hv.z*w.y; A2.z += hv.z*w.z; A2.w += hv.z*w.w;
            A3.x += hv.w*w.x; A3.y += hv.w*w.y; A3.z += hv.w*w.z; A3.w += hv.w*w.w;
        }
        __syncthreads();   // previous chunk's edge reads of Tc/he_s complete
        *(float4*)&Tc[aT][nT+0][fT] = A0;
        *(float4*)&Tc[aT][nT+1][fT] = A1;
        *(float4*)&Tc[aT][nT+2][fT] = A2;
        *(float4*)&Tc[aT][nT+3][fT] = A3;
        {   // stage he chunk: 128 edge slots x 8 a, float2 per thread
            int le = t >> 2, a2 = (t & 3)*2;
            int e = ebase + le;
            if (e < NE)
                *(float2*)&he_s[le][a2] =
                    *(const float2*)&he_srt[(size_t)e*64 + ac + a2];
        }
        __syncthreads();   // chunk ready

        // ---- edge stage: accumulate partial msg in registers ----
        if (nl0 >= 0) {
            float4 hA = *(const float4*)&he_s[slot][0];
            float4 hB = *(const float4*)&he_s[slot][4];
            float4 t0 = *(const float4*)&Tc[0][nl0][f4];
            float4 t1 = *(const float4*)&Tc[1][nl0][f4];
            float4 t2 = *(const float4*)&Tc[2][nl0][f4];
            float4 t3 = *(const float4*)&Tc[3][nl0][f4];
            float4 t4 = *(const float4*)&Tc[4][nl0][f4];
            float4 t5 = *(const float4*)&Tc[5][nl0][f4];
            float4 t6 = *(const float4*)&Tc[6][nl0][f4];
            float4 t7 = *(const float4*)&Tc[7][nl0][f4];
            m0.x += hA.x*t0.x+hA.y*t1.x+hA.z*t2.x+hA.w*t3.x+hB.x*t4.x+hB.y*t5.x+hB.z*t6.x+hB.w*t7.x;
            m0.y += hA.x*t0.y+hA.y*t1.y+hA.z*t2.y+hA.w*t3.y+hB.x*t4.y+hB.y*t5.y+hB.z*t6.y+hB.w*t7.y;
            m0.z += hA.x*t0.z+hA.y*t1.z+hA.z*t2.z+hA.w*t3.z+hB.x*t4.z+hB.y*t5.z+hB.z*t6.z+hB.w*t7.z;
            m0.w += hA.x*t0.w+hA.y*t1.w+hA.z*t2.w+hA.w*t3.w+hB.x*t4.w+hB.y*t5.w+hB.z*t6.w+hB.w*t7.w;
        }
        if (nl1 >= 0) {
            float4 hA = *(const float4*)&he_s[32+slot][0];
            float4 hB = *(const float4*)&he_s[32+slot][4];
            float4 t0 = *(const float4*)&Tc[0][nl1][f4];
            float4 t1 = *(const float4*)&Tc[1][nl1][f4];
            float4 t2 = *(const float4*)&Tc[2][nl1][f4];
            float4 t3 = *(const float4*)&Tc[3][nl1][f4];
            float4 t4 = *(const float4*)&Tc[4][nl1][f4];
            float4 t5 = *(const float4*)&Tc[5][nl1][f4];
            float4 t6 = *(const float4*)&Tc[6][nl1][f4];
            float4 t7 = *(const float4*)&Tc[7][nl1][f4];
            m1.x += hA.x*t0.x+hA.y*t1.x+hA.z*t2.x+hA.w*t3.x+hB.x*t4.x+hB.y*t5.x+hB.z*t6.x+hB.w*t7.x;
            m1.y += hA.x*t0.y+hA.y*t1.y+hA.z*t2.y+hA.w*t3.y+hB.x*t4.y+hB.y*t5.y+hB.z*t6.y+hB.w*t7.y;
            m1.z += hA.x*t0.z+hA.y*t1.z+hA.z*t2.z+hA.w*t3.z+hB.x*t4.z+hB.y*t5.z+hB.z*t6.z+hB.w*t7.z;
            m1.w += hA.x*t0.w+hA.y*t1.w+hA.z*t2.w+hA.w*t3.w+hB.x*t4.w+hB.y*t5.w+hB.z*t6.w+hB.w*t7.w;
        }
        if (nl2 >= 0) {
            float4 hA = *(const float4*)&he_s[64+slot][0];
            float4 hB = *(const float4*)&he_s[64+slot][4];
            float4 t0 = *(const float4*)&Tc[0][nl2][f4];
            float4 t1 = *(const float4*)&Tc[1][nl2][f4];
            float4 t2 = *(const float4*)&Tc[2][nl2][f4];
            float4 t3 = *(const float4*)&Tc[3][nl2][f4];
            float4 t4 = *(const float4*)&Tc[4][nl2][f4];
            float4 t5 = *(const float4*)&Tc[5][nl2][f4];
            float4 t6 = *(const float4*)&Tc[6][nl2][f4];
            float4 t7 = *(const float4*)&Tc[7][nl2][f4];
            m2.x += hA.x*t0.x+hA.y*t1.x+hA.z*t2.x+hA.w*t3.x+hB.x*t4.x+hB.y*t5.x+hB.z*t6.x+hB.w*t7.x;
            m2.y += hA.x*t0.y+hA.y*t1.y+hA.z*t2.y+hA.w*t3.y+hB.x*t4.y+hB.y*t5.y+hB.z*t6.y+hB.w*t7.y;
            m2.z += hA.x*t0.z+hA.y*t1.z+hA.z*t2.z+hA.w*t3.z+hB.x*t4.z+hB.y*t5.z+hB.z*t6.z+hB.w*t7.z;
            m2.w += hA.x*t0.w+hA.y*t1.w+hA.z*t2.w+hA.w*t3.w+hB.x*t4.w+hB.y*t5.w+hB.z*t6.w+hB.w*t7.w;
        }
        if (nl3 >= 0) {
            float4 hA = *(const float4*)&he_s[96+slot][0];
            float4 hB = *(const float4*)&he_s[96+slot][4];
            float4 t0 = *(const float4*)&Tc[0][nl3][f4];
            float4 t1 = *(const float4*)&Tc[1][nl3][f4];
            float4 t2 = *(const float4*)&Tc[2][nl3][f4];
            float4 t3 = *(const float4*)&Tc[3][nl3][f4];
            float4 t4 = *(const float4*)&Tc[4][nl3][f4];
            float4 t5 = *(const float4*)&Tc[5][nl3][f4];
            float4 t6 = *(const float4*)&Tc[6][nl3][f4];
            float4 t7 = *(const float4*)&Tc[7][nl3][f4];
            m3.x += hA.x*t0.x+hA.y*t1.x+hA.z*t2.x+hA.w*t3.x+hB.x*t4.x+hB.y*t5.x+hB.z*t6.x+hB.w*t7.x;
            m3.y += hA.x*t0.y+hA.y*t1.y+hA.z*t2.y+hA.w*t3.y+hB.x*t4.y+hB.y*t5.y+hB.z*t6.y+hB.w*t7.y;
            m3.z += hA.x*t0.z+hA.y*t1.z+hA.z*t2.z+hA.w*t3.z+hB.x*t4.z+hB.y*t5.z+hB.z*t6.z+hB.w*t7.z;
            m3.w += hA.x*t0.w+hA.y*t1.w+hA.z*t2.w+hA.w*t3.w+hB.x*t4.w+hB.y*t5.w+hB.z*t6.w+hB.w*t7.w;
        }
        // overflow fallback (>128 edges in a tile): direct per-chunk atomics
        for (int e = ebase + 128 + slot; e < eend; e += 32) {
            int nl = srcs[e] - n0, dt = dsts[e];
            const float* hep = he_srt + (size_t)e*64 + ac;
            float4 pm = {0,0,0,0};
            #pragma unroll
            for (int a = 0; a < ACH; ++a) {
                float hv = hep[a];
                float4 tv = *(const float4*)&Tc[a][nl][f4];
                pm.x += hv*tv.x; pm.y += hv*tv.y; pm.z += hv*tv.z; pm.w += hv*tv.w;
            }
            if (blockIdx.y == 0 && c == 0) {
                float4 b = *(const float4*)&Tb[nl][f4];
                pm.x += b.x; pm.y += b.y; pm.z += b.z; pm.w += b.w;
            }
            float* ap = aggp + (size_t)dt*64 + f4;
            atomicAdd(ap+0, pm.x); atomicAdd(ap+1, pm.y);
            atomicAdd(ap+2, pm.z); atomicAdd(ap+3, pm.w);
        }
    }

    // ---- scatter: one atomic add per edge (msg + bias on y==0) ----
    bool addb = (blockIdx.y == 0);
    if (nl0 >= 0) {
        float4 b = addb ? *(const float4*)&Tb[nl0][f4] : make_float4(0,0,0,0);
        float* ap = aggp + (size_t)dt0*64 + f4;
        atomicAdd(ap+0, m0.x+b.x); atomicAdd(ap+1, m0.y+b.y);
        atomicAdd(ap+2, m0.z+b.z); atomicAdd(ap+3, m0.w+b.w);
    }
    if (nl1 >= 0) {
        float4 b = addb ? *(const float4*)&Tb[nl1][f4] : make_float4(0,0,0,0);
        float* ap = aggp + (size_t)dt1*64 + f4;
        atomicAdd(ap+0, m1.x+b.x); atomicAdd(ap+1, m1.y+b.y);
        atomicAdd(ap+2, m1.z+b.z); atomicAdd(ap+3, m1.w+b.w);
    }
    if (nl2 >= 0) {
        float4 b = addb ? *(const float4*)&Tb[nl2][f4] : make_float4(0,0,0,0);
        float* ap = aggp + (size_t)dt2*64 + f4;
        atomicAdd(ap+0, m2.x+b.x); atomicAdd(ap+1, m2.y+b.y);
        atomicAdd(ap+2, m2.z+b.z); atomicAdd(ap+3, m2.w+b.w);
    }
    if (nl3 >= 0) {
        float4 b = addb ? *(const float4*)&Tb[nl3][f4] : make_float4(0,0,0,0);
        float* ap = aggp + (size_t)dt3*64 + f4;
        atomicAdd(ap+0, m3.x+b.x); atomicAdd(ap+1, m3.y+b.y);
        atomicAdd(ap+2, m3.z+b.z); atomicAdd(ap+3, m3.w+b.w);
    }
}

// ---------------- node kernel: m, gi, gh + GRU; thread = (node, gate-col) ----
// 8 nodes / 512 threads / grid 512. Weights streamed from L2 via packed
// W8T[k][g][8] (2 x b128 per k). Sums both agg halves, zeroes them for the
// next conv iteration.
__global__ __launch_bounds__(512) void node_kernel(
    const float* __restrict__ W8T, const float* __restrict__ root,
    const float* __restrict__ conv_b, const float* __restrict__ inv_deg,
    const float* __restrict__ bih, const float* __restrict__ bhh,
    float* __restrict__ h, float* __restrict__ agg)
{
    __shared__ float hs[8][64];
    __shared__ float ms[8][64];
    int t = threadIdx.x;
    int n = t >> 6, g = t & 63;
    int gn = blockIdx.x*8 + n;
    hs[n][g] = h[(size_t)gn*64 + g];
    __syncthreads();
    {   // m = lrelu((agg0+agg1)*inv_deg + h@root + conv_b)
        size_t ix = (size_t)gn*64 + g;
        float v = (agg[ix] + agg[(size_t)NN*64 + ix])*inv_deg[gn] + conv_b[g];
        agg[ix] = 0.f;
        agg[(size_t)NN*64 + ix] = 0.f;     // ready for next iteration's conv
        #pragma unroll 8
        for (int k = 0; k < 64; ++k) v += hs[n][k]*root[k*64 + g];
        ms[n][g] = lrelu(v);
    }
    __syncthreads();

    float ir=0.f, iz=0.f, in_=0.f, hr=0.f, hz=0.f, hn=0.f;
    const float* Wp = W8T + (size_t)g*8;
    #pragma unroll 8
    for (int k = 0; k < 64; ++k) {
        float am = ms[n][k], ah = hs[n][k];
        float4 w0 = *(const float4*)(Wp + (size_t)k*512);
        float4 w1 = *(const float4*)(Wp + (size_t)k*512 + 4);
        ir  += am*w0.x; iz += am*w0.y; in_ += am*w0.z;
        hr  += ah*w0.w; hz += ah*w1.x; hn  += ah*w1.y;
    }
    float r  = sigm(ir + bih[g]      + hr + bhh[g]);
    float z  = sigm(iz + bih[64+g]   + hz + bhh[64+g]);
    float nn = tanhf(in_ + bih[128+g] + r*(hn + bhh[128+g]));
    h[(size_t)gn*64 + g] = (1.f - z)*nn + z*hs[n][g];
}

// ---------------- finale ----------------
__device__ __forceinline__ float q_val(const float* lbih, const float* lbhh, int g)
{
    float gi = lbih[g]     + lbhh[g];
    float gg = lbih[128+g] + lbhh[128+g];
    float go = lbih[192+g] + lbhh[192+g];
    return sigm(go)*tanhf(sigm(gi)*tanhf(gg));   // hl0=cl0=q_star0=0
}

__global__ __launch_bounds__(256) void e_kernel(
    const float* __restrict__ h, const float* __restrict__ lbih,
    const float* __restrict__ lbhh, float* __restrict__ e)
{
    __shared__ float qs[64];
    int t = threadIdx.x;
    if (t < 64) qs[t] = q_val(lbih, lbhh, t);
    __syncthreads();
    int w = t >> 6, f = t & 63;
    int n = blockIdx.x*4 + w;
    float p = h[(size_t)n*64 + f]*qs[f];
    #pragma unroll
    for (int off = 32; off; off >>= 1) p += __shfl_xor(p, off);
    if (f == 0) e[n] = p;
}

__global__ __launch_bounds__(1024) void pool_kernel(
    const float* __restrict__ h, float* __restrict__ e,
    const int* __restrict__ gstart, const int* __restrict__ gend,
    const float* __restrict__ lbih, const float* __restrict__ lbhh,
    const float* __restrict__ Wout, const float* __restrict__ bout,
    float* __restrict__ out)
{
    __shared__ float red[1024];
    __shared__ float rp[64];
    __shared__ float sval;
    int g = blockIdx.x, t = threadIdx.x;
    int s = gstart[g], en = gend[g];

    float mx = -1e30f;
    for (int n = s+t; n < en; n += 1024) mx = fmaxf(mx, e[n]);
    red[t] = mx; __syncthreads();
    for (int st = 512; st; st >>= 1) { if (t < st) red[t] = fmaxf(red[t], red[t+st]); __syncthreads(); }
    if (t == 0) sval = red[0];
    __syncthreads();
    float lmx = sval;
    __syncthreads();

    float sm = 0.f;
    for (int n = s+t; n < en; n += 1024) { float a = expf(e[n]-lmx); e[n] = a; sm += a; }
    red[t] = sm; __syncthreads();
    for (int st = 512; st; st >>= 1) { if (t < st) red[t] += red[t+st]; __syncthreads(); }
    if (t == 0) sval = (red[0] > 0.f) ? 1.f/red[0] : 0.f;
    __syncthreads();
    float inv_asum = sval;
    __syncthreads();

    int w = t >> 6, f = t & 63;
    float racc = 0.f;
    for (int n = s+w; n < en; n += 16) racc += e[n]*h[(size_t)n*64 + f];
    red[t] = racc; __syncthreads();
    if (w == 0) {
        float a = 0.f;
        #pragma unroll
        for (int i = 0; i < 16; ++i) a += red[i*64 + f];
        rp[f] = a*inv_asum;
    }
    __syncthreads();

    if (t < 64) {
        float qv = q_val(lbih, lbhh, t);
        float p0 = qv*Wout[t*2]   + rp[t]*Wout[(64+t)*2];
        float p1 = qv*Wout[t*2+1] + rp[t]*Wout[(64+t)*2+1];
        #pragma unroll
        for (int off = 32; off; off >>= 1) { p0 += __shfl_xor(p0, off); p1 += __shfl_xor(p1, off); }
        if (t == 0) { out[g*2] = p0 + bout[0]; out[g*2+1] = p1 + bout[1]; }
    }
}

extern "C" void kernel_launch(void* const* d_in, const int* in_sizes, int n_in,
                              void* d_out, int out_size, void* d_ws, size_t ws_size,
                              hipStream_t stream)
{
    const float* x      = (const float*)d_in[0];
    const float* ea     = (const float*)d_in[1];
    const int*   ei     = (const int*)  d_in[2];
    const int*   batch  = (const int*)  d_in[3];
    const float* W0     = (const float*)d_in[4];
    const float* b0     = (const float*)d_in[5];
    const float* We1    = (const float*)d_in[6];
    const float* be1    = (const float*)d_in[7];
    const float* We2    = (const float*)d_in[8];
    const float* be2    = (const float*)d_in[9];
    const float* root   = (const float*)d_in[10];
    const float* conv_b = (const float*)d_in[11];
    const float* Wih    = (const float*)d_in[12];
    const float* Whh    = (const float*)d_in[13];
    const float* bih    = (const float*)d_in[14];
    const float* bhh    = (const float*)d_in[15];
    const float* lbih   = (const float*)d_in[18];
    const float* lbhh   = (const float*)d_in[19];
    const float* Wout   = (const float*)d_in[20];
    const float* bout   = (const float*)d_in[21];
    float* out = (float*)d_out;

    float* W = (float*)d_ws;
    size_t off = 0;
    float* h       = W + off; off += (size_t)NN*64;
    float* he      = W + off; off += (size_t)NE*64;
    float* he_srt  = W + off; off += (size_t)NE*64;
    float* agg     = W + off; off += (size_t)2*NN*64;   // two halves (y=0, y=1)
    float* W8T     = W + off; off += 32768;
    float* inv_deg = W + off; off += NN;
    float* e       = W + off; off += NN;
    int*   deg     = (int*)(W + off); off += NN;   // deg+cnt contiguous: one memset
    int*   cnt     = (int*)(W + off); off += NN;
    int*   offs    = (int*)(W + off); off += NN+1;
    int*   srcs    = (int*)(W + off); off += NE;
    int*   dsts    = (int*)(W + off); off += NE;
    int*   perm    = (int*)(W + off); off += NE;
    int*   gstart  = (int*)(W + off); off += BG;
    int*   gend    = (int*)(W + off); off += BG;

    hipMemsetAsync(deg, 0, 2*NN*sizeof(int), stream);
    hipMemsetAsync(agg, 0, (size_t)2*NN*64*sizeof(float), stream);
    setup_kernel<<<4096, 256, 0, stream>>>(x, ea, ei, W0, b0, We1, be1, Wih, Whh,
                                           W8T, h, he, deg, cnt);
    scan_kernel<<<1, 256, 0, stream>>>(cnt, offs);
    scatter_kernel<<<64, 256, 0, stream>>>(ei, offs, cnt, srcs, dsts, perm);
    reorder_kernel<<<4096, 256, 0, stream>>>(he, perm, he_srt);
    inv_range_kernel<<<16, 256, 0, stream>>>(deg, batch, inv_deg, gstart, gend);

    for (int it = 0; it < 6; ++it) {
        conv_kernel<<<dim3(NN/NT, 2), 512, 0, stream>>>(h, We2, be2, he_srt,
                                                        offs, srcs, dsts, agg);
        node_kernel<<<NN/8, 512, 0, stream>>>(W8T, root, conv_b,
                                              inv_deg, bih, bhh, h, agg);
    }

    e_kernel<<<NN/4, 256, 0, stream>>>(h, lbih, lbhh, e);
    pool_kernel<<<BG, 1024, 0, stream>>>(h, e, gstart, gend, lbih, lbhh, Wout, bout, out);
}

// Round 5
// 557.952 us; speedup vs baseline: 1.1490x; 1.1490x over previous
//
#include <hip/hip_runtime.h>
#include <cstddef>

#define NE 16384
#define NN 4096
#define BG 16
#define NT 16      // nodes per conv tile
#define ACH 8      // a-chunk size (8 chunks of 8 = 64), double-buffered

__device__ __forceinline__ float lrelu(float v){ return v >= 0.f ? v : 0.01f*v; }
__device__ __forceinline__ float sigm(float v){ return 1.f/(1.f + expf(-v)); }

// ---------------- setup: W8T, h0, he, deg(dst), cnt(src) ----------------
__global__ __launch_bounds__(256) void setup_kernel(
    const float* __restrict__ x, const float* __restrict__ ea,
    const int* __restrict__ ei,
    const float* __restrict__ W0, const float* __restrict__ b0,
    const float* __restrict__ We1, const float* __restrict__ be1,
    const float* __restrict__ Wih, const float* __restrict__ Whh,
    float* __restrict__ W8T,
    float* __restrict__ h, float* __restrict__ he,
    int* __restrict__ deg, int* __restrict__ cnt)
{
    int t = blockIdx.x*256 + threadIdx.x;   // grid: 4096x256 = 1048576
    {   // he: [E,64]  lrelu(edge_attr @ We1 + be1)
        int e = t >> 6, f = t & 63;
        float v = be1[f];
        #pragma unroll
        for (int d = 0; d < 4; ++d) v += ea[e*4+d]*We1[d*64+f];
        he[t] = lrelu(v);
    }
    if (t < NN*64) {    // h0 = lrelu(x @ W0 + b0)
        int n = t >> 6, f = t & 63;
        float v = b0[f];
        #pragma unroll
        for (int d = 0; d < 3; ++d) v += x[n*3+d]*W0[d*64+f];
        h[t] = lrelu(v);
    }
    if (t < 32768) {    // W8T[k][g][8] = {Wih_r,Wih_z,Wih_n,Whh_r,Whh_z,Whh_n,0,0}
        int k = t >> 9, g = (t >> 3) & 63, j = t & 7;
        float v = 0.f;
        if (j < 3)      v = Wih[(j*64+g)*64 + k];
        else if (j < 6) v = Whh[((j-3)*64+g)*64 + k];
        W8T[t] = v;
    }
    if (t < NE) {
        atomicAdd(&deg[ei[NE + t]], 1);   // in-degree (dst) for mean aggr
        atomicAdd(&cnt[ei[t]], 1);        // out-degree (src) for edge sort
    }
}

// ---------------- exclusive scan of cnt[4096] -> offs[4097] (1 block) ----------------
__global__ __launch_bounds__(256) void scan_kernel(const int* __restrict__ cnt,
                                                   int* __restrict__ offs)
{
    __shared__ int ps[256];
    int t = threadIdx.x;
    int base = t*16;
    int loc[16];
    int s = 0;
    #pragma unroll
    for (int i = 0; i < 16; ++i) { loc[i] = s; s += cnt[base+i]; }
    ps[t] = s; __syncthreads();
    for (int off = 1; off < 256; off <<= 1) {
        int v = 0;
        if (t >= off) v = ps[t-off];
        __syncthreads();
        if (t >= off) ps[t] += v;
        __syncthreads();
    }
    int pre = (t == 0) ? 0 : ps[t-1];
    #pragma unroll
    for (int i = 0; i < 16; ++i) offs[base+i] = pre + loc[i];
    if (t == 255) offs[NN] = pre + s;
}

// ---------------- scatter: build src-sorted edge arrays ----------------
__global__ __launch_bounds__(256) void scatter_kernel(
    const int* __restrict__ ei, const int* __restrict__ offs,
    int* __restrict__ cnt,  // consumed as cursor via atomicSub
    int* __restrict__ srcs, int* __restrict__ dsts, int* __restrict__ perm)
{
    int e = blockIdx.x*256 + threadIdx.x;
    if (e >= NE) return;
    int s = ei[e], d = ei[NE + e];
    int old = atomicSub(&cnt[s], 1);
    int pos = offs[s] + old - 1;
    srcs[pos] = s; dsts[pos] = d; perm[pos] = e;
}

// ---------------- gather he rows into src-sorted order ----------------
__global__ __launch_bounds__(256) void reorder_kernel(
    const float* __restrict__ he, const int* __restrict__ perm,
    float* __restrict__ he_srt)
{
    int t = blockIdx.x*256 + threadIdx.x;   // 4096 x 256 = NE*64
    he_srt[t] = he[(size_t)perm[t>>6]*64 + (t & 63)];
}

// ---------------- inv_deg + per-graph node ranges ----------------
__global__ __launch_bounds__(256) void inv_range_kernel(
    const int* __restrict__ deg, const int* __restrict__ batch,
    float* __restrict__ inv_deg, int* __restrict__ gstart, int* __restrict__ gend)
{
    int n = blockIdx.x*256 + threadIdx.x;   // 16 blocks -> 4096
    if (n >= NN) return;
    inv_deg[n] = 1.f / fmaxf((float)deg[n], 1.f);
    int b  = batch[n];
    int bp = (n == 0)    ? -1 : batch[n-1];
    int bn = (n == NN-1) ? BG : batch[n+1];
    for (int g = bp+1; g <= b; ++g) gstart[g] = n;
    for (int g = b;   g <  bn; ++g) gend[g]   = n+1;
    if (n == 0)    for (int g = 0;   g < b;  ++g) gend[g]   = 0;
    if (n == NN-1) for (int g = b+1; g < BG; ++g) gstart[g] = NN;
}

// ---------------- fused conv: producer/consumer wave role-split ----------------
// One 1024-thread block per 16-node tile. Waves 0-7 (t<512) = PRODUCERS:
// compute T chunk c (8 a-values) into Tc[c&1] each phase. Waves 8-15 =
// CONSUMERS: stage he chunk c into he_s[c&1] and consume chunk c-1
// (Tc[(c-1)&1], he_s[(c-1)&1]) accumulating per-edge messages in registers.
// One barrier per phase; buffers alternate by parity so producer VALU overlaps
// consumer LDS (rounds 1-4 showed barrier-lockstep phases serialize at
// ~30us of LDS-pipe time; this overlaps them without needing >1 block/CU).
__global__ __launch_bounds__(1024) void conv_kernel(
    const float* __restrict__ h, const float* __restrict__ We2,
    const float* __restrict__ be2, const float* __restrict__ he_srt,
    const int* __restrict__ offs, const int* __restrict__ srcs,
    const int* __restrict__ dsts, float* __restrict__ agg)
{
    __shared__ float hsT[64][NT];          // 4 KB
    __shared__ float Tb [NT][64];          // 4 KB
    __shared__ float Tc [2][ACH][NT][64];  // 64 KB (double-buffered)
    __shared__ float he_s[2][128][ACH];    // 8 KB  (double-buffered) -> 80 KB
    int t  = threadIdx.x;
    int n0 = blockIdx.x * NT;

    { int n = t >> 6, i = t & 63; hsT[i][n] = h[(size_t)(n0+n)*64 + i]; }
    int ebase = offs[n0];
    int ecnt  = offs[n0+NT] - ebase;
    int eend  = ebase + ecnt;
    __syncthreads();

    // producer mapping (t < 512)
    int aT = t >> 6;               // 0..7  a' within chunk
    int nT = ((t >> 4) & 3) * 4;   // 4 nodes per thread
    int fT = (t & 15) * 4;         // 4 f per thread
    // consumer mapping + persistent state (t >= 512)
    int ct   = t - 512;
    int slot = ct >> 4;            // 0..31 edge slots
    int f4   = (ct & 15) * 4;      // 4 output features per thread
    int nl0=-1,dt0=0,nl1=-1,dt1=0,nl2=-1,dt2=0,nl3=-1,dt3=0;
    float4 m0={0,0,0,0},m1={0,0,0,0},m2={0,0,0,0},m3={0,0,0,0};
    if (t >= 512) {
        if (slot      < ecnt) { nl0 = srcs[ebase+slot]    - n0; dt0 = dsts[ebase+slot];    }
        if (slot + 32 < ecnt) { nl1 = srcs[ebase+slot+32] - n0; dt1 = dsts[ebase+slot+32]; }
        if (slot + 64 < ecnt) { nl2 = srcs[ebase+slot+64] - n0; dt2 = dsts[ebase+slot+64]; }
        if (slot + 96 < ecnt) { nl3 = srcs[ebase+slot+96] - n0; dt3 = dsts[ebase+slot+96]; }
    }

#define EDGE_ACC(mj, nlj, row, buf_) \
    if (nlj >= 0) { \
        float4 hA = *(const float4*)&he_s[buf_][row][0]; \
        float4 hB = *(const float4*)&he_s[buf_][row][4]; \
        float4 t0 = *(const float4*)&Tc[buf_][0][nlj][f4]; \
        float4 t1 = *(const float4*)&Tc[buf_][1][nlj][f4]; \
        float4 t2 = *(const float4*)&Tc[buf_][2][nlj][f4]; \
        float4 t3 = *(const float4*)&Tc[buf_][3][nlj][f4]; \
        float4 t4 = *(const float4*)&Tc[buf_][4][nlj][f4]; \
        float4 t5 = *(const float4*)&Tc[buf_][5][nlj][f4]; \
        float4 t6 = *(const float4*)&Tc[buf_][6][nlj][f4]; \
        float4 t7 = *(const float4*)&Tc[buf_][7][nlj][f4]; \
        mj.x += hA.x*t0.x+hA.y*t1.x+hA.z*t2.x+hA.w*t3.x+hB.x*t4.x+hB.y*t5.x+hB.z*t6.x+hB.w*t7.x; \
        mj.y += hA.x*t0.y+hA.y*t1.y+hA.z*t2.y+hA.w*t3.y+hB.x*t4.y+hB.y*t5.y+hB.z*t6.y+hB.w*t7.y; \
        mj.z += hA.x*t0.z+hA.y*t1.z+hA.z*t2.z+hA.w*t3.z+hB.x*t4.z+hB.y*t5.z+hB.z*t6.z+hB.w*t7.z; \
        mj.w += hA.x*t0.w+hA.y*t1.w+hA.z*t2.w+hA.w*t3.w+hB.x*t4.w+hB.y*t5.w+hB.z*t6.w+hB.w*t7.w; \
    }

#define CONSUME(cm) { \
    int buf_ = (cm) & 1; \
    EDGE_ACC(m0, nl0, (slot),      buf_) \
    EDGE_ACC(m1, nl1, (slot+32),   buf_) \
    EDGE_ACC(m2, nl2, (slot+64),   buf_) \
    EDGE_ACC(m3, nl3, (slot+96),   buf_) \
    for (int e = ebase + 128 + slot; e < eend; e += 32) { \
        int nl = srcs[e] - n0, dtv = dsts[e]; \
        const float* hep = he_srt + (size_t)e*64 + (cm)*ACH; \
        float4 pm = {0,0,0,0}; \
        _Pragma("unroll") \
        for (int a = 0; a < ACH; ++a) { \
            float hv = hep[a]; \
            float4 tv = *(const float4*)&Tc[buf_][a][nl][f4]; \
            pm.x += hv*tv.x; pm.y += hv*tv.y; pm.z += hv*tv.z; pm.w += hv*tv.w; \
        } \
        if ((cm) == 0) { \
            float4 b = *(const float4*)&Tb[nl][f4]; \
            pm.x += b.x; pm.y += b.y; pm.z += b.z; pm.w += b.w; \
        } \
        float* ap = agg + (size_t)dtv*64 + f4; \
        atomicAdd(ap+0, pm.x); atomicAdd(ap+1, pm.y); \
        atomicAdd(ap+2, pm.z); atomicAdd(ap+3, pm.w); \
    } \
}

    for (int c = 0; c < 8; ++c) {
        if (t < 512) {
            // ---- producer: T chunk c -> Tc[c&1] ----
            const float* Wp = We2 + (size_t)(c*ACH + aT)*4096 + fT;
            float4 A0={0,0,0,0},A1={0,0,0,0},A2={0,0,0,0},A3={0,0,0,0};
            #pragma unroll 8
            for (int i = 0; i < 64; ++i) {
                float4 w  = *(const float4*)(Wp + (size_t)i*64);
                float4 hv = *(const float4*)&hsT[i][nT];
                A0.x += hv.x*w.x; A0.y += hv.x*w.y; A0.z += hv.x*w.z; A0.w += hv.x*w.w;
                A1.x += hv.y*w.x; A1.y += hv.y*w.y; A1.z += hv.y*w.z; A1.w += hv.y*w.w;
                A2.x += hv.z*w.x; A2.y += hv.z*w.y; A2.z += hv.z*w.z; A2.w += hv.z*w.w;
                A3.x += hv.w*w.x; A3.y += hv.w*w.y; A3.z += hv.w*w.z; A3.w += hv.w*w.w;
            }
            int buf = c & 1;
            *(float4*)&Tc[buf][aT][nT+0][fT] = A0;
            *(float4*)&Tc[buf][aT][nT+1][fT] = A1;
            *(float4*)&Tc[buf][aT][nT+2][fT] = A2;
            *(float4*)&Tc[buf][aT][nT+3][fT] = A3;
            if (c == 0) {   // Tb[n][f] = sum_i h[n,i]*be2[i*64+f]  (2 vals/thread)
                #pragma unroll
                for (int r = 0; r < 2; ++r) {
                    int idx = t + r*512;
                    int n = idx >> 6, f = idx & 63;
                    float acc = 0.f;
                    #pragma unroll 8
                    for (int i = 0; i < 64; ++i) acc += hsT[i][n]*be2[i*64+f];
                    Tb[n][f] = acc;
                }
            }
        } else {
            {   // ---- consumer: stage he chunk c (consumed next phase) ----
                int le = ct >> 2, a2 = (ct & 3) * 2;
                if (ebase + le < NE)
                    *(float2*)&he_s[c&1][le][a2] =
                        *(const float2*)&he_srt[(size_t)(ebase+le)*64 + c*ACH + a2];
            }
            if (c >= 1) CONSUME(c-1);
        }
        __syncthreads();
    }
    if (t >= 512) {
        CONSUME(7);
        // ---- scatter: one atomic add per edge (msg + bias) ----
        if (nl0 >= 0) {
            float4 b = *(const float4*)&Tb[nl0][f4];
            float* ap = agg + (size_t)dt0*64 + f4;
            atomicAdd(ap+0, m0.x+b.x); atomicAdd(ap+1, m0.y+b.y);
            atomicAdd(ap+2, m0.z+b.z); atomicAdd(ap+3, m0.w+b.w);
        }
        if (nl1 >= 0) {
            float4 b = *(const float4*)&Tb[nl1][f4];
            float* ap = agg + (size_t)dt1*64 + f4;
            atomicAdd(ap+0, m1.x+b.x); atomicAdd(ap+1, m1.y+b.y);
            atomicAdd(ap+2, m1.z+b.z); atomicAdd(ap+3, m1.w+b.w);
        }
        if (nl2 >= 0) {
            float4 b = *(const float4*)&Tb[nl2][f4];
            float* ap = agg + (size_t)dt2*64 + f4;
            atomicAdd(ap+0, m2.x+b.x); atomicAdd(ap+1, m2.y+b.y);
            atomicAdd(ap+2, m2.z+b.z); atomicAdd(ap+3, m2.w+b.w);
        }
        if (nl3 >= 0) {
            float4 b = *(const float4*)&Tb[nl3][f4];
            float* ap = agg + (size_t)dt3*64 + f4;
            atomicAdd(ap+0, m3.x+b.x); atomicAdd(ap+1, m3.y+b.y);
            atomicAdd(ap+2, m3.z+b.z); atomicAdd(ap+3, m3.w+b.w);
        }
    }
#undef CONSUME
#undef EDGE_ACC
}

// ---------------- node kernel: m, gi, gh + GRU; thread = (node, gate-col) ----
// 8 nodes / 512 threads / grid 512. Weights streamed from L2 via packed
// W8T[k][g][8] (2 x b128 per k). Zeroes agg for the next conv iteration.
__global__ __launch_bounds__(512) void node_kernel(
    const float* __restrict__ W8T, const float* __restrict__ root,
    const float* __restrict__ conv_b, const float* __restrict__ inv_deg,
    const float* __restrict__ bih, const float* __restrict__ bhh,
    float* __restrict__ h, float* __restrict__ agg)
{
    __shared__ float hs[8][64];
    __shared__ float ms[8][64];
    int t = threadIdx.x;
    int n = t >> 6, g = t & 63;
    int gn = blockIdx.x*8 + n;
    hs[n][g] = h[(size_t)gn*64 + g];
    __syncthreads();
    {   // m = lrelu(agg*inv_deg + h@root + conv_b)
        size_t ix = (size_t)gn*64 + g;
        float v = agg[ix]*inv_deg[gn] + conv_b[g];
        agg[ix] = 0.f;                     // ready for next iteration's conv
        #pragma unroll 8
        for (int k = 0; k < 64; ++k) v += hs[n][k]*root[k*64 + g];
        ms[n][g] = lrelu(v);
    }
    __syncthreads();

    float ir=0.f, iz=0.f, in_=0.f, hr=0.f, hz=0.f, hn=0.f;
    const float* Wp = W8T + (size_t)g*8;
    #pragma unroll 8
    for (int k = 0; k < 64; ++k) {
        float am = ms[n][k], ah = hs[n][k];
        float4 w0 = *(const float4*)(Wp + (size_t)k*512);
        float4 w1 = *(const float4*)(Wp + (size_t)k*512 + 4);
        ir  += am*w0.x; iz += am*w0.y; in_ += am*w0.z;
        hr  += ah*w0.w; hz += ah*w1.x; hn  += ah*w1.y;
    }
    float r  = sigm(ir + bih[g]      + hr + bhh[g]);
    float z  = sigm(iz + bih[64+g]   + hz + bhh[64+g]);
    float nn = tanhf(in_ + bih[128+g] + r*(hn + bhh[128+g]));
    h[(size_t)gn*64 + g] = (1.f - z)*nn + z*hs[n][g];
}

// ---------------- finale ----------------
__device__ __forceinline__ float q_val(const float* lbih, const float* lbhh, int g)
{
    float gi = lbih[g]     + lbhh[g];
    float gg = lbih[128+g] + lbhh[128+g];
    float go = lbih[192+g] + lbhh[192+g];
    return sigm(go)*tanhf(sigm(gi)*tanhf(gg));   // hl0=cl0=q_star0=0
}

__global__ __launch_bounds__(256) void e_kernel(
    const float* __restrict__ h, const float* __restrict__ lbih,
    const float* __restrict__ lbhh, float* __restrict__ e)
{
    __shared__ float qs[64];
    int t = threadIdx.x;
    if (t < 64) qs[t] = q_val(lbih, lbhh, t);
    __syncthreads();
    int w = t >> 6, f = t & 63;
    int n = blockIdx.x*4 + w;
    float p = h[(size_t)n*64 + f]*qs[f];
    #pragma unroll
    for (int off = 32; off; off >>= 1) p += __shfl_xor(p, off);
    if (f == 0) e[n] = p;
}

__global__ __launch_bounds__(1024) void pool_kernel(
    const float* __restrict__ h, float* __restrict__ e,
    const int* __restrict__ gstart, const int* __restrict__ gend,
    const float* __restrict__ lbih, const float* __restrict__ lbhh,
    const float* __restrict__ Wout, const float* __restrict__ bout,
    float* __restrict__ out)
{
    __shared__ float red[1024];
    __shared__ float rp[64];
    __shared__ float sval;
    int g = blockIdx.x, t = threadIdx.x;
    int s = gstart[g], en = gend[g];

    float mx = -1e30f;
    for (int n = s+t; n < en; n += 1024) mx = fmaxf(mx, e[n]);
    red[t] = mx; __syncthreads();
    for (int st = 512; st; st >>= 1) { if (t < st) red[t] = fmaxf(red[t], red[t+st]); __syncthreads(); }
    if (t == 0) sval = red[0];
    __syncthreads();
    float lmx = sval;
    __syncthreads();

    float sm = 0.f;
    for (int n = s+t; n < en; n += 1024) { float a = expf(e[n]-lmx); e[n] = a; sm += a; }
    red[t] = sm; __syncthreads();
    for (int st = 512; st; st >>= 1) { if (t < st) red[t] += red[t+st]; __syncthreads(); }
    if (t == 0) sval = (red[0] > 0.f) ? 1.f/red[0] : 0.f;
    __syncthreads();
    float inv_asum = sval;
    __syncthreads();

    int w = t >> 6, f = t & 63;
    float racc = 0.f;
    for (int n = s+w; n < en; n += 16) racc += e[n]*h[(size_t)n*64 + f];
    red[t] = racc; __syncthreads();
    if (w == 0) {
        float a = 0.f;
        #pragma unroll
        for (int i = 0; i < 16; ++i) a += red[i*64 + f];
        rp[f] = a*inv_asum;
    }
    __syncthreads();

    if (t < 64) {
        float qv = q_val(lbih, lbhh, t);
        float p0 = qv*Wout[t*2]   + rp[t]*Wout[(64+t)*2];
        float p1 = qv*Wout[t*2+1] + rp[t]*Wout[(64+t)*2+1];
        #pragma unroll
        for (int off = 32; off; off >>= 1) { p0 += __shfl_xor(p0, off); p1 += __shfl_xor(p1, off); }
        if (t == 0) { out[g*2] = p0 + bout[0]; out[g*2+1] = p1 + bout[1]; }
    }
}

extern "C" void kernel_launch(void* const* d_in, const int* in_sizes, int n_in,
                              void* d_out, int out_size, void* d_ws, size_t ws_size,
                              hipStream_t stream)
{
    const float* x      = (const float*)d_in[0];
    const float* ea     = (const float*)d_in[1];
    const int*   ei     = (const int*)  d_in[2];
    const int*   batch  = (const int*)  d_in[3];
    const float* W0     = (const float*)d_in[4];
    const float* b0     = (const float*)d_in[5];
    const float* We1    = (const float*)d_in[6];
    const float* be1    = (const float*)d_in[7];
    const float* We2    = (const float*)d_in[8];
    const float* be2    = (const float*)d_in[9];
    const float* root   = (const float*)d_in[10];
    const float* conv_b = (const float*)d_in[11];
    const float* Wih    = (const float*)d_in[12];
    const float* Whh    = (const float*)d_in[13];
    const float* bih    = (const float*)d_in[14];
    const float* bhh    = (const float*)d_in[15];
    const float* lbih   = (const float*)d_in[18];
    const float* lbhh   = (const float*)d_in[19];
    const float* Wout   = (const float*)d_in[20];
    const float* bout   = (const float*)d_in[21];
    float* out = (float*)d_out;

    float* W = (float*)d_ws;
    size_t off = 0;
    float* h       = W + off; off += (size_t)NN*64;
    float* he      = W + off; off += (size_t)NE*64;
    float* he_srt  = W + off; off += (size_t)NE*64;
    float* agg     = W + off; off += (size_t)NN*64;
    float* W8T     = W + off; off += 32768;
    float* inv_deg = W + off; off += NN;
    float* e       = W + off; off += NN;
    int*   deg     = (int*)(W + off); off += NN;   // deg+cnt contiguous: one memset
    int*   cnt     = (int*)(W + off); off += NN;
    int*   offs    = (int*)(W + off); off += NN+1;
    int*   srcs    = (int*)(W + off); off += NE;
    int*   dsts    = (int*)(W + off); off += NE;
    int*   perm    = (int*)(W + off); off += NE;
    int*   gstart  = (int*)(W + off); off += BG;
    int*   gend    = (int*)(W + off); off += BG;

    hipMemsetAsync(deg, 0, 2*NN*sizeof(int), stream);
    hipMemsetAsync(agg, 0, (size_t)NN*64*sizeof(float), stream);
    setup_kernel<<<4096, 256, 0, stream>>>(x, ea, ei, W0, b0, We1, be1, Wih, Whh,
                                           W8T, h, he, deg, cnt);
    scan_kernel<<<1, 256, 0, stream>>>(cnt, offs);
    scatter_kernel<<<64, 256, 0, stream>>>(ei, offs, cnt, srcs, dsts, perm);
    reorder_kernel<<<4096, 256, 0, stream>>>(he, perm, he_srt);
    inv_range_kernel<<<16, 256, 0, stream>>>(deg, batch, inv_deg, gstart, gend);

    for (int it = 0; it < 6; ++it) {
        conv_kernel<<<NN/NT, 1024, 0, stream>>>(h, We2, be2, he_srt,
                                                offs, srcs, dsts, agg);
        node_kernel<<<NN/8, 512, 0, stream>>>(W8T, root, conv_b,
                                              inv_deg, bih, bhh, h, agg);
    }

    e_kernel<<<NN/4, 256, 0, stream>>>(h, lbih, lbhh, e);
    pool_kernel<<<BG, 1024, 0, stream>>>(h, e, gstart, gend, lbih, lbhh, Wout, bout, out);
}